// Round 5
// baseline (390.215 us; speedup 1.0000x reference)
//
#include <hip/hip_runtime.h>
#include <hip/hip_bf16.h>
#include <stdint.h>

#define DM 1024   // d_model
#define DD 512    // d (proj out / head dim)
#define BB 32     // batch
#define LL 1024   // seq len
#define SCALE 0.04419417382415922f  // 1/sqrt(512)
#define MAT ((size_t)BB * LL * DD)  // elems per q/k/v matrix

typedef float f32x4 __attribute__((ext_vector_type(4)));
typedef short bf16x8 __attribute__((ext_vector_type(8)));
typedef short bf16x4 __attribute__((ext_vector_type(4)));

__device__ inline unsigned short f2bf(float f) {
    union { float f; uint32_t u; } v; v.f = f;
    uint32_t r = v.u + 0x7fffu + ((v.u >> 16) & 1u);
    return (unsigned short)(r >> 16);
}

__device__ inline bf16x4 cvt4(f32x4 a, float s) {
    bf16x4 r;
    r[0] = (short)f2bf(a[0] * s);
    r[1] = (short)f2bf(a[1] * s);
    r[2] = (short)f2bf(a[2] * s);
    r[3] = (short)f2bf(a[3] * s);
    return r;
}

#define GLOAD_LDS16(gsrc, ldst) \
    __builtin_amdgcn_global_load_lds((const __attribute__((address_space(1))) unsigned int*)(gsrc), \
        (__attribute__((address_space(3))) unsigned int*)(ldst), 16, 0, 0)

// drain own async loads, then publish across the workgroup
__device__ inline void publish_barrier() {
    asm volatile("s_waitcnt vmcnt(0)" ::: "memory");
    __builtin_amdgcn_sched_barrier(0);
    __builtin_amdgcn_s_barrier();
    __builtin_amdgcn_sched_barrier(0);
}

// ---------------------------------------------------------------------------
// Kernel 0a: cast x fp32 -> bf16 (dest: d_out reused as scratch; dead by attn)
// ---------------------------------------------------------------------------
__global__ __launch_bounds__(256) void cast_x(const float* __restrict__ x,
                                              unsigned short* __restrict__ xb)
{
    size_t idx = (size_t)blockIdx.x * 256 + threadIdx.x;
    size_t base = idx * 8;
    f32x4 a = *(const f32x4*)(x + base);
    f32x4 b = *(const f32x4*)(x + base + 4);
    bf16x4 lo = cvt4(a, 1.0f), hi = cvt4(b, 1.0f);
    bf16x8 o = {lo[0], lo[1], lo[2], lo[3], hi[0], hi[1], hi[2], hi[3]};
    *(bf16x8*)(xb + base) = o;
}

// ---------------------------------------------------------------------------
// Kernel 0b: cast Wq/Wk/Wv fp32 -> bf16 (Wq pre-scaled by 1/sqrt(D))
// ---------------------------------------------------------------------------
__global__ __launch_bounds__(256) void cast_w(const float* __restrict__ Wq,
                                              const float* __restrict__ Wk,
                                              const float* __restrict__ Wv,
                                              unsigned short* __restrict__ Wb)
{
    size_t idx = (size_t)blockIdx.x * 256 + threadIdx.x;   // 0..196607
    int o = (int)(idx >> 16);
    size_t rem = idx & 65535;
    const float* W = (o == 0) ? Wq : (o == 1) ? Wk : Wv;
    float s = (o == 0) ? SCALE : 1.0f;
    size_t base = rem * 8;
    f32x4 a = *(const f32x4*)(W + base);
    f32x4 b = *(const f32x4*)(W + base + 4);
    bf16x4 lo = cvt4(a, s), hi = cvt4(b, s);
    bf16x8 out = {lo[0], lo[1], lo[2], lo[3], hi[0], hi[1], hi[2], hi[3]};
    *(bf16x8*)(Wb + (size_t)o * 524288 + base) = out;
}

// ---------------------------------------------------------------------------
// Kernel 1: q/k/v projection v3 (unchanged from round 4).
// ---------------------------------------------------------------------------
__global__ __launch_bounds__(256, 2) void qkv_proj3(
    const unsigned short* __restrict__ xb,   // [32768][1024] bf16
    const unsigned short* __restrict__ Wb,   // [3][512][1024] bf16 (q pre-scaled)
    const float* __restrict__ bq, const float* __restrict__ bk, const float* __restrict__ bv,
    unsigned short* __restrict__ qkv)
{
    __shared__ __align__(16) unsigned short At[2][8192];  // [buf][128 rows][128 B]
    __shared__ __align__(16) unsigned short Bt[2][8192];  // 64 KB total

    const int o = blockIdx.y;
    const float* bias = (o == 0) ? bq : (o == 1) ? bk : bv;
    const float wscale = (o == 0) ? SCALE : 1.0f;
    const unsigned short* W = Wb + (size_t)o * 524288;
    unsigned short* out = qkv + (size_t)o * MAT;

    int wg = blockIdx.x;
    wg = (wg & 7) * 128 + (wg >> 3);           // XCD swizzle (bijective, 1024 = 8*128)
    const int rowbase = (wg >> 2) * 128;
    const int colbase = (wg & 3) * 128;

    const int tid  = threadIdx.x;
    const int lane = tid & 63;
    const int w    = tid >> 6;
    const int wr   = (w >> 1) * 64;
    const int wc   = (w & 1) * 64;
    const int l15  = lane & 15, l4 = lane >> 4;

    const int r8   = lane >> 3;                // row within 8-row group
    const int swch = (lane & 7) ^ r8;          // pre-swizzled source chunk

    const char* xpanel = (const char*)(xb + (size_t)rowbase * DM);
    const char* wpanel = (const char*)(W  + (size_t)colbase * DM);

    f32x4 acc[4][4];
    #pragma unroll
    for (int i = 0; i < 4; ++i)
        #pragma unroll
        for (int j = 0; j < 4; ++j)
            acc[i][j] = (f32x4){0.f, 0.f, 0.f, 0.f};

    #define STAGE_AB(KK, BUF) do {                                               \
        _Pragma("unroll")                                                        \
        for (int i2 = 0; i2 < 4; ++i2) {                                         \
            int grp = i2 * 4 + w;                                                \
            size_t rowoff = (size_t)(grp * 8 + r8) * 2048 + (KK) * 2 + swch * 16;\
            GLOAD_LDS16(xpanel + rowoff, (char*)&At[BUF][0] + grp * 1024);       \
            GLOAD_LDS16(wpanel + rowoff, (char*)&Bt[BUF][0] + grp * 1024);       \
        }                                                                        \
    } while (0)

    STAGE_AB(0, 0);
    __syncthreads();

    for (int t = 0; t < 16; ++t) {
        const int cur = t & 1;
        if (t < 15) STAGE_AB((t + 1) * 64, cur ^ 1);

        const char* Ab = (const char*)&At[cur][0];
        const char* Bb = (const char*)&Bt[cur][0];
        #pragma unroll
        for (int ks = 0; ks < 2; ++ks) {
            bf16x8 af[4], bf_[4];
            const int ch = (ks * 4 + l4) ^ (l15 & 7);
            #pragma unroll
            for (int m = 0; m < 4; ++m) {
                int row = wr + m * 16 + l15;
                af[m] = *(const bf16x8*)(Ab + row * 128 + (ch << 4));
            }
            #pragma unroll
            for (int n = 0; n < 4; ++n) {
                int row = wc + n * 16 + l15;
                bf_[n] = *(const bf16x8*)(Bb + row * 128 + (ch << 4));
            }
            #pragma unroll
            for (int n = 0; n < 4; ++n)
                #pragma unroll
                for (int m = 0; m < 4; ++m)
                    acc[m][n] = __builtin_amdgcn_mfma_f32_16x16x32_bf16(af[m], bf_[n], acc[m][n], 0, 0, 0);
        }

        if (t < 15) publish_barrier();
    }
    #undef STAGE_AB

    #pragma unroll
    for (int n = 0; n < 4; ++n) {
        int col = colbase + wc + n * 16 + l15;
        float bv_ = bias[col] * wscale;
        #pragma unroll
        for (int m = 0; m < 4; ++m) {
            int row0 = rowbase + wr + m * 16 + l4 * 4;
            #pragma unroll
            for (int r = 0; r < 4; ++r)
                out[(size_t)(row0 + r) * DD + col] = f2bf(acc[m][n][r] + bv_);
        }
    }
}

// ---------------------------------------------------------------------------
// Kernel 2: V transpose.  v[b][l][d] -> vt[b][d][l]  (bf16)
// ---------------------------------------------------------------------------
__global__ __launch_bounds__(256) void vtrans(const unsigned short* __restrict__ v,
                                              unsigned short* __restrict__ vt)
{
    __shared__ unsigned short T[64][72];
    const int lt = blockIdx.x, dt = blockIdx.y, b = blockIdx.z;
    const int t = threadIdx.x;
    const unsigned short* src = v + ((size_t)(b * LL + lt * 64)) * DD + dt * 64;
    #pragma unroll
    for (int it = 0; it < 2; ++it) {
        int r  = (t >> 3) + it * 32;
        int c0 = (t & 7) * 8;
        bf16x8 x = *(const bf16x8*)(src + (size_t)r * DD + c0);
        *(bf16x4*)&T[r][c0]     = (bf16x4){x[0], x[1], x[2], x[3]};
        *(bf16x4*)&T[r][c0 + 4] = (bf16x4){x[4], x[5], x[6], x[7]};
    }
    __syncthreads();
    unsigned short* dst = vt + ((size_t)(b * DD + dt * 64)) * LL + lt * 64;
    #pragma unroll
    for (int it = 0; it < 2; ++it) {
        int d  = (t >> 3) + it * 32;
        int c0 = (t & 7) * 8;
        bf16x8 o;
        #pragma unroll
        for (int e = 0; e < 8; ++e) o[e] = T[c0 + e][d];
        *(bf16x8*)(dst + (size_t)d * LL + c0) = o;
    }
}

// ---------------------------------------------------------------------------
// Kernel 3: flash attention v4 — single-buffered K and V, phase-rotated
// staging, 74.2 KB LDS -> 2 blocks/CU (2 waves/SIMD).
// Per tile: [vmcnt0+bar] (K(jt) published, Vbuf free) ; issue V(jt) ;
// QK^T(K) ; softmax ; [vmcnt0+bar] (V(jt) published, Kbuf free) ;
// issue K(jt+1) ; PV(V).  Every stage hides under a full compute phase, and
// the co-resident partner block fills any remaining drain.
// ---------------------------------------------------------------------------
__global__ __launch_bounds__(256, 2) void attn4(
    const unsigned short* __restrict__ qkv,
    const unsigned short* __restrict__ vt,
    const int* __restrict__ mask,
    float* __restrict__ outp)
{
    __shared__ __align__(16) unsigned short KtL[16384];   // [32 keys][512 d] = 32 KB
    __shared__ __align__(16) unsigned short VtL[16384];   // [512 d][32 keys] = 32 KB
    __shared__ __align__(16) unsigned short Pw[4][16][36]; // 4.5 KB
    __shared__ float mbias[1024];                          // 4 KB; total 74,240 B

    const int bx = blockIdx.x;
    const int h = bx >> 8, i = bx & 255;
    const int b = i & 31;
    const int qtx = (i >> 5) & 7;
    const int qt = h ? qtx : 15 - qtx;   // heavy+light pair co-resident per CU

    const int tid = threadIdx.x, lane = tid & 63, w = tid >> 6;
    const int l15 = lane & 15, l4 = lane >> 4;
    const int lsw = lane * 16;

    const unsigned short* q = qkv;
    const unsigned short* k = qkv + MAT;
    const char* kb  = (const char*)k + ((size_t)b * LL) * DD * 2;   // row = 1024 B
    const char* vtb = (const char*)vt + ((size_t)b * DD) * LL * 2;  // row = 2048 B

    {
        const int* mp = mask + b * LL;
        #pragma unroll
        for (int j = 0; j < 4; ++j)
            mbias[tid * 4 + j] = mp[tid * 4 + j] ? 0.0f : -1e30f;
    }

    bf16x8 qf[16];
    {
        const unsigned short* qp = q + ((size_t)(b * LL + qt * 64 + w * 16 + l15)) * DD + l4 * 8;
        #pragma unroll
        for (int ks = 0; ks < 16; ++ks)
            qf[ks] = *(const bf16x8*)(qp + ks * 32);
    }

    f32x4 oacc[32];
    #pragma unroll
    for (int n = 0; n < 32; ++n) oacc[n] = (f32x4){0.f, 0.f, 0.f, 0.f};
    float mrow[4] = {-1e30f, -1e30f, -1e30f, -1e30f};
    float lrow[4] = {0.f, 0.f, 0.f, 0.f};

    const int jtmax = 2 * qt + 1;

    #define STAGE_K(JT) do {                                                    \
        const char* kt = kb + ((size_t)(JT) << 15);                             \
        _Pragma("unroll")                                                       \
        for (int i2 = 0; i2 < 8; ++i2) {                                        \
            int row = i2 * 4 + w;                                               \
            GLOAD_LDS16(kt + (row << 10) + (lsw ^ ((row & 7) << 4)),            \
                        (char*)KtL + (row << 10));                              \
        }                                                                       \
    } while (0)

    #define STAGE_V(JT) do {                                                    \
        const char* vtj = vtb + ((size_t)(JT) << 6);                            \
        _Pragma("unroll")                                                       \
        for (int i2 = 0; i2 < 8; ++i2) {                                        \
            int c0 = i2 * 256 + w * 64;                                         \
            int c  = c0 + lane;                                                 \
            GLOAD_LDS16(vtj + ((size_t)(c >> 2) << 11) + ((c & 3) << 4),        \
                        (char*)VtL + c0 * 16);                                  \
        }                                                                       \
    } while (0)

    STAGE_K(0);

    const int swz = (l15 & 7) << 4;

    for (int jt = 0; jt <= jtmax; ++jt) {
        // K(jt) published by all waves; Vbuf free (all waves past PV(jt-1));
        // mbias/first-K visible on iter 0.
        publish_barrier();
        STAGE_V(jt);

        // ---- QK^T: S[16 own rows][32 keys] from swizzled K LDS ----
        f32x4 sacc[2];
        sacc[0] = (f32x4){0.f, 0.f, 0.f, 0.f};
        sacc[1] = (f32x4){0.f, 0.f, 0.f, 0.f};
        #pragma unroll
        for (int ks = 0; ks < 16; ++ks) {
            int coloff = ((ks << 6) + (l4 << 4)) ^ swz;
            #pragma unroll
            for (int nf = 0; nf < 2; ++nf) {
                const bf16x8 kf = *(const bf16x8*)((const char*)KtL + ((nf * 16 + l15) << 10) + coloff);
                sacc[nf] = __builtin_amdgcn_mfma_f32_16x16x32_bf16(qf[ks], kf, sacc[nf], 0, 0, 0);
            }
        }

        // ---- mask + causal + online softmax (in-register) ----
        const bool diag = (jt >= 2 * qt);
        float s[2][4];
        #pragma unroll
        for (int nf = 0; nf < 2; ++nf) {
            float bb_ = mbias[jt * 32 + nf * 16 + l15];
            #pragma unroll
            for (int r = 0; r < 4; ++r) {
                float val = sacc[nf][r] + bb_;
                if (diag) {
                    int gi = qt * 64 + w * 16 + l4 * 4 + r;
                    int gj = jt * 32 + nf * 16 + l15;
                    val = (gj <= gi) ? val : -3e38f;
                }
                s[nf][r] = val;
            }
        }
        float pm[4];
        #pragma unroll
        for (int r = 0; r < 4; ++r) {
            float mx = fmaxf(s[0][r], s[1][r]);
            mx = fmaxf(mx, __shfl_xor(mx, 1));
            mx = fmaxf(mx, __shfl_xor(mx, 2));
            mx = fmaxf(mx, __shfl_xor(mx, 4));
            mx = fmaxf(mx, __shfl_xor(mx, 8));
            pm[r] = mx;
        }
        bool need = false;
        #pragma unroll
        for (int r = 0; r < 4; ++r) need |= (pm[r] - mrow[r] > 8.0f);
        if (__any(need)) {
            #pragma unroll
            for (int r = 0; r < 4; ++r) {
                float mn = fmaxf(mrow[r], pm[r]);
                float corr = __expf(mrow[r] - mn);
                mrow[r] = mn;
                lrow[r] *= corr;
                #pragma unroll
                for (int n = 0; n < 32; ++n) oacc[n][r] *= corr;
            }
        }
        #pragma unroll
        for (int r = 0; r < 4; ++r) {
            float ls = 0.f;
            #pragma unroll
            for (int nf = 0; nf < 2; ++nf) {
                float p = __expf(s[nf][r] - mrow[r]);
                ls += p;
                Pw[w][l4 * 4 + r][nf * 16 + l15] = f2bf(p);
            }
            ls += __shfl_xor(ls, 1);
            ls += __shfl_xor(ls, 2);
            ls += __shfl_xor(ls, 4);
            ls += __shfl_xor(ls, 8);
            lrow[r] += ls;
        }

        // V(jt) published by all waves; Kbuf free (all waves past QK^T(jt)).
        publish_barrier();
        if (jt < jtmax) STAGE_K(jt + 1);

        // ---- PV: O[16 rows][512] += P[16][32] * V[32][512] (V from LDS) ----
        const bf16x8 pa = *(const bf16x8*)&Pw[w][l15][l4 * 8];
        #pragma unroll
        for (int n = 0; n < 32; ++n) {
            const bf16x8 vb_ = *(const bf16x8*)((const char*)VtL + ((n * 16 + l15) << 6) + (l4 << 4));
            oacc[n] = __builtin_amdgcn_mfma_f32_16x16x32_bf16(pa, vb_, oacc[n], 0, 0, 0);
        }
    }

    // ---- epilogue: relu(O / l) ----
    float inv[4];
    #pragma unroll
    for (int r = 0; r < 4; ++r) inv[r] = 1.0f / lrow[r];
    float* op = outp + ((size_t)(b * LL + qt * 64 + w * 16 + l4 * 4)) * DD + l15;
    #pragma unroll
    for (int n = 0; n < 32; ++n)
        #pragma unroll
        for (int r = 0; r < 4; ++r)
            op[(size_t)r * DD + n * 16] = fmaxf(oacc[n][r] * inv[r], 0.f);
    #undef STAGE_K
    #undef STAGE_V
}

extern "C" void kernel_launch(void* const* d_in, const int* in_sizes, int n_in,
                              void* d_out, int out_size, void* d_ws, size_t ws_size,
                              hipStream_t stream) {
    const float* x  = (const float*)d_in[0];
    const float* Wq = (const float*)d_in[1];
    const float* bq = (const float*)d_in[2];
    const float* Wk = (const float*)d_in[3];
    const float* bk = (const float*)d_in[4];
    const float* Wv = (const float*)d_in[5];
    const float* bv = (const float*)d_in[6];
    const int* mask = (const int*)d_in[7];

    unsigned short* qkv = (unsigned short*)d_ws;          // q|k|v bf16
    unsigned short* v   = qkv + 2 * MAT;
    unsigned short* vtp = qkv + 3 * MAT;                  // vt region
    unsigned short* Wb  = vtp;                            // parked, overwritten by vtrans
    unsigned short* xb  = (unsigned short*)d_out;         // x bf16 scratch
    float* out = (float*)d_out;

    cast_x<<<16384, 256, 0, stream>>>(x, xb);
    cast_w<<<768, 256, 0, stream>>>(Wq, Wk, Wv, Wb);
    qkv_proj3<<<dim3(1024, 3), 256, 0, stream>>>(xb, Wb, bq, bk, bv, qkv);
    vtrans<<<dim3(16, 8, 32), 256, 0, stream>>>(v, vtp);
    attn4<<<dim3(512), 256, 0, stream>>>(qkv, vtp, mask, out);
}

// Round 6
// 322.830 us; speedup vs baseline: 1.2087x; 1.2087x over previous
//
#include <hip/hip_runtime.h>
#include <hip/hip_bf16.h>
#include <stdint.h>

#define DM 1024   // d_model
#define DD 512    // d (proj out / head dim)
#define BB 32     // batch
#define LL 1024   // seq len
#define SCALE 0.04419417382415922f  // 1/sqrt(512)
#define MAT ((size_t)BB * LL * DD)  // elems per q/k/v matrix

typedef float f32x4 __attribute__((ext_vector_type(4)));
typedef short bf16x8 __attribute__((ext_vector_type(8)));
typedef short bf16x4 __attribute__((ext_vector_type(4)));

__device__ inline unsigned short f2bf(float f) {
    union { float f; uint32_t u; } v; v.f = f;
    uint32_t r = v.u + 0x7fffu + ((v.u >> 16) & 1u);
    return (unsigned short)(r >> 16);
}

__device__ inline bf16x4 cvt4(f32x4 a, float s) {
    bf16x4 r;
    r[0] = (short)f2bf(a[0] * s);
    r[1] = (short)f2bf(a[1] * s);
    r[2] = (short)f2bf(a[2] * s);
    r[3] = (short)f2bf(a[3] * s);
    return r;
}

#define GLOAD_LDS16(gsrc, ldst) \
    __builtin_amdgcn_global_load_lds((const __attribute__((address_space(1))) unsigned int*)(gsrc), \
        (__attribute__((address_space(3))) unsigned int*)(ldst), 16, 0, 0)

// drain own async loads, then publish across the workgroup
__device__ inline void publish_barrier() {
    asm volatile("s_waitcnt vmcnt(0)" ::: "memory");
    __builtin_amdgcn_sched_barrier(0);
    __builtin_amdgcn_s_barrier();
    __builtin_amdgcn_sched_barrier(0);
}

// ---------------------------------------------------------------------------
// Kernel 0a: cast x fp32 -> bf16 (dest: d_out reused as scratch; dead by attn)
// ---------------------------------------------------------------------------
__global__ __launch_bounds__(256) void cast_x(const float* __restrict__ x,
                                              unsigned short* __restrict__ xb)
{
    size_t idx = (size_t)blockIdx.x * 256 + threadIdx.x;
    size_t base = idx * 8;
    f32x4 a = *(const f32x4*)(x + base);
    f32x4 b = *(const f32x4*)(x + base + 4);
    bf16x4 lo = cvt4(a, 1.0f), hi = cvt4(b, 1.0f);
    bf16x8 o = {lo[0], lo[1], lo[2], lo[3], hi[0], hi[1], hi[2], hi[3]};
    *(bf16x8*)(xb + base) = o;
}

// ---------------------------------------------------------------------------
// Kernel 0b: cast Wq/Wk/Wv fp32 -> bf16 (Wq pre-scaled by 1/sqrt(D))
// ---------------------------------------------------------------------------
__global__ __launch_bounds__(256) void cast_w(const float* __restrict__ Wq,
                                              const float* __restrict__ Wk,
                                              const float* __restrict__ Wv,
                                              unsigned short* __restrict__ Wb)
{
    size_t idx = (size_t)blockIdx.x * 256 + threadIdx.x;   // 0..196607
    int o = (int)(idx >> 16);
    size_t rem = idx & 65535;
    const float* W = (o == 0) ? Wq : (o == 1) ? Wk : Wv;
    float s = (o == 0) ? SCALE : 1.0f;
    size_t base = rem * 8;
    f32x4 a = *(const f32x4*)(W + base);
    f32x4 b = *(const f32x4*)(W + base + 4);
    bf16x4 lo = cvt4(a, s), hi = cvt4(b, s);
    bf16x8 out = {lo[0], lo[1], lo[2], lo[3], hi[0], hi[1], hi[2], hi[3]};
    *(bf16x8*)(Wb + (size_t)o * 524288 + base) = out;
}

// ---------------------------------------------------------------------------
// Kernel 1: q/k/v projection v3 (unchanged from round 4; 137 us, 0 conflicts).
// ---------------------------------------------------------------------------
__global__ __launch_bounds__(256, 2) void qkv_proj3(
    const unsigned short* __restrict__ xb,   // [32768][1024] bf16
    const unsigned short* __restrict__ Wb,   // [3][512][1024] bf16 (q pre-scaled)
    const float* __restrict__ bq, const float* __restrict__ bk, const float* __restrict__ bv,
    unsigned short* __restrict__ qkv)
{
    __shared__ __align__(16) unsigned short At[2][8192];  // [buf][128 rows][128 B]
    __shared__ __align__(16) unsigned short Bt[2][8192];  // 64 KB total

    const int o = blockIdx.y;
    const float* bias = (o == 0) ? bq : (o == 1) ? bk : bv;
    const float wscale = (o == 0) ? SCALE : 1.0f;
    const unsigned short* W = Wb + (size_t)o * 524288;
    unsigned short* out = qkv + (size_t)o * MAT;

    int wg = blockIdx.x;
    wg = (wg & 7) * 128 + (wg >> 3);           // XCD swizzle (bijective, 1024 = 8*128)
    const int rowbase = (wg >> 2) * 128;
    const int colbase = (wg & 3) * 128;

    const int tid  = threadIdx.x;
    const int lane = tid & 63;
    const int w    = tid >> 6;
    const int wr   = (w >> 1) * 64;
    const int wc   = (w & 1) * 64;
    const int l15  = lane & 15, l4 = lane >> 4;

    const int r8   = lane >> 3;                // row within 8-row group
    const int swch = (lane & 7) ^ r8;          // pre-swizzled source chunk

    const char* xpanel = (const char*)(xb + (size_t)rowbase * DM);
    const char* wpanel = (const char*)(W  + (size_t)colbase * DM);

    f32x4 acc[4][4];
    #pragma unroll
    for (int i = 0; i < 4; ++i)
        #pragma unroll
        for (int j = 0; j < 4; ++j)
            acc[i][j] = (f32x4){0.f, 0.f, 0.f, 0.f};

    #define STAGE_AB(KK, BUF) do {                                               \
        _Pragma("unroll")                                                        \
        for (int i2 = 0; i2 < 4; ++i2) {                                         \
            int grp = i2 * 4 + w;                                                \
            size_t rowoff = (size_t)(grp * 8 + r8) * 2048 + (KK) * 2 + swch * 16;\
            GLOAD_LDS16(xpanel + rowoff, (char*)&At[BUF][0] + grp * 1024);       \
            GLOAD_LDS16(wpanel + rowoff, (char*)&Bt[BUF][0] + grp * 1024);       \
        }                                                                        \
    } while (0)

    STAGE_AB(0, 0);
    __syncthreads();

    for (int t = 0; t < 16; ++t) {
        const int cur = t & 1;
        if (t < 15) STAGE_AB((t + 1) * 64, cur ^ 1);

        const char* Ab = (const char*)&At[cur][0];
        const char* Bb = (const char*)&Bt[cur][0];
        #pragma unroll
        for (int ks = 0; ks < 2; ++ks) {
            bf16x8 af[4], bf_[4];
            const int ch = (ks * 4 + l4) ^ (l15 & 7);
            #pragma unroll
            for (int m = 0; m < 4; ++m) {
                int row = wr + m * 16 + l15;
                af[m] = *(const bf16x8*)(Ab + row * 128 + (ch << 4));
            }
            #pragma unroll
            for (int n = 0; n < 4; ++n) {
                int row = wc + n * 16 + l15;
                bf_[n] = *(const bf16x8*)(Bb + row * 128 + (ch << 4));
            }
            #pragma unroll
            for (int n = 0; n < 4; ++n)
                #pragma unroll
                for (int m = 0; m < 4; ++m)
                    acc[m][n] = __builtin_amdgcn_mfma_f32_16x16x32_bf16(af[m], bf_[n], acc[m][n], 0, 0, 0);
        }

        if (t < 15) publish_barrier();
    }
    #undef STAGE_AB

    #pragma unroll
    for (int n = 0; n < 4; ++n) {
        int col = colbase + wc + n * 16 + l15;
        float bv_ = bias[col] * wscale;
        #pragma unroll
        for (int m = 0; m < 4; ++m) {
            int row0 = rowbase + wr + m * 16 + l4 * 4;
            #pragma unroll
            for (int r = 0; r < 4; ++r)
                out[(size_t)(row0 + r) * DD + col] = f2bf(acc[m][n][r] + bv_);
        }
    }
}

// ---------------------------------------------------------------------------
// Kernel 2: V transpose.  v[b][l][d] -> vt[b][d][l]  (bf16)
// ---------------------------------------------------------------------------
__global__ __launch_bounds__(256) void vtrans(const unsigned short* __restrict__ v,
                                              unsigned short* __restrict__ vt)
{
    __shared__ unsigned short T[64][72];
    const int lt = blockIdx.x, dt = blockIdx.y, b = blockIdx.z;
    const int t = threadIdx.x;
    const unsigned short* src = v + ((size_t)(b * LL + lt * 64)) * DD + dt * 64;
    #pragma unroll
    for (int it = 0; it < 2; ++it) {
        int r  = (t >> 3) + it * 32;
        int c0 = (t & 7) * 8;
        bf16x8 x = *(const bf16x8*)(src + (size_t)r * DD + c0);
        *(bf16x4*)&T[r][c0]     = (bf16x4){x[0], x[1], x[2], x[3]};
        *(bf16x4*)&T[r][c0 + 4] = (bf16x4){x[4], x[5], x[6], x[7]};
    }
    __syncthreads();
    unsigned short* dst = vt + ((size_t)(b * DD + dt * 64)) * LL + lt * 64;
    #pragma unroll
    for (int it = 0; it < 2; ++it) {
        int d  = (t >> 3) + it * 32;
        int c0 = (t & 7) * 8;
        bf16x8 o;
        #pragma unroll
        for (int e = 0; e < 8; ++e) o[e] = T[c0 + e][d];
        *(bf16x8*)(dst + (size_t)d * LL + c0) = o;
    }
}

// ---------------------------------------------------------------------------
// Kernel 3: flash attention v4b — single-buffered K and V, phase-rotated
// staging, 74.2 KB LDS. NO launch_bounds occupancy directive: round-5's
// (256,2) capped unified VGPR/AGPR to 128 and spilled ~30 MB to scratch
// (VGPR_Count 128, WRITE_SIZE +29MB, MfmaUtil 0.4%). With free allocation
// (~228 regs) the HW still fits 2 blocks/CU (2x228 <= 512/SIMD pool,
// 2x74.2KB <= 160KB).
// Per tile: [vmcnt0+bar] (K(jt) published, Vbuf free) ; issue V(jt) ;
// QK^T(K) ; softmax ; [vmcnt0+bar] (V(jt) published, Kbuf free) ;
// issue K(jt+1) ; PV(V).
// ---------------------------------------------------------------------------
__global__ __launch_bounds__(256) void attn4(
    const unsigned short* __restrict__ qkv,
    const unsigned short* __restrict__ vt,
    const int* __restrict__ mask,
    float* __restrict__ outp)
{
    __shared__ __align__(16) unsigned short KtL[16384];   // [32 keys][512 d] = 32 KB
    __shared__ __align__(16) unsigned short VtL[16384];   // [512 d][32 keys] = 32 KB
    __shared__ __align__(16) unsigned short Pw[4][16][36]; // 4.5 KB
    __shared__ float mbias[1024];                          // 4 KB; total 74,240 B

    const int bx = blockIdx.x;
    const int h = bx >> 8, i = bx & 255;
    const int b = i & 31;
    const int qtx = (i >> 5) & 7;
    const int qt = h ? qtx : 15 - qtx;   // heavy+light pair co-resident per CU

    const int tid = threadIdx.x, lane = tid & 63, w = tid >> 6;
    const int l15 = lane & 15, l4 = lane >> 4;
    const int lsw = lane * 16;

    const unsigned short* q = qkv;
    const unsigned short* k = qkv + MAT;
    const char* kb  = (const char*)k + ((size_t)b * LL) * DD * 2;   // row = 1024 B
    const char* vtb = (const char*)vt + ((size_t)b * DD) * LL * 2;  // row = 2048 B

    {
        const int* mp = mask + b * LL;
        #pragma unroll
        for (int j = 0; j < 4; ++j)
            mbias[tid * 4 + j] = mp[tid * 4 + j] ? 0.0f : -1e30f;
    }

    bf16x8 qf[16];
    {
        const unsigned short* qp = q + ((size_t)(b * LL + qt * 64 + w * 16 + l15)) * DD + l4 * 8;
        #pragma unroll
        for (int ks = 0; ks < 16; ++ks)
            qf[ks] = *(const bf16x8*)(qp + ks * 32);
    }

    f32x4 oacc[32];
    #pragma unroll
    for (int n = 0; n < 32; ++n) oacc[n] = (f32x4){0.f, 0.f, 0.f, 0.f};
    float mrow[4] = {-1e30f, -1e30f, -1e30f, -1e30f};
    float lrow[4] = {0.f, 0.f, 0.f, 0.f};

    const int jtmax = 2 * qt + 1;

    #define STAGE_K(JT) do {                                                    \
        const char* kt = kb + ((size_t)(JT) << 15);                             \
        _Pragma("unroll")                                                       \
        for (int i2 = 0; i2 < 8; ++i2) {                                        \
            int row = i2 * 4 + w;                                               \
            GLOAD_LDS16(kt + (row << 10) + (lsw ^ ((row & 7) << 4)),            \
                        (char*)KtL + (row << 10));                              \
        }                                                                       \
    } while (0)

    #define STAGE_V(JT) do {                                                    \
        const char* vtj = vtb + ((size_t)(JT) << 6);                            \
        _Pragma("unroll")                                                       \
        for (int i2 = 0; i2 < 8; ++i2) {                                        \
            int c0 = i2 * 256 + w * 64;                                         \
            int c  = c0 + lane;                                                 \
            GLOAD_LDS16(vtj + ((size_t)(c >> 2) << 11) + ((c & 3) << 4),        \
                        (char*)VtL + c0 * 16);                                  \
        }                                                                       \
    } while (0)

    STAGE_K(0);
    __syncthreads();   // lgkm-drains mbias ds_writes + vm-drains K(0); all published

    const int swz = (l15 & 7) << 4;

    for (int jt = 0; jt <= jtmax; ++jt) {
        // K(jt) published by all waves; Vbuf free (all waves past PV(jt-1)).
        publish_barrier();
        STAGE_V(jt);

        // ---- QK^T: S[16 own rows][32 keys] from swizzled K LDS ----
        f32x4 sacc[2];
        sacc[0] = (f32x4){0.f, 0.f, 0.f, 0.f};
        sacc[1] = (f32x4){0.f, 0.f, 0.f, 0.f};
        #pragma unroll
        for (int ks = 0; ks < 16; ++ks) {
            int coloff = ((ks << 6) + (l4 << 4)) ^ swz;
            #pragma unroll
            for (int nf = 0; nf < 2; ++nf) {
                const bf16x8 kf = *(const bf16x8*)((const char*)KtL + ((nf * 16 + l15) << 10) + coloff);
                sacc[nf] = __builtin_amdgcn_mfma_f32_16x16x32_bf16(qf[ks], kf, sacc[nf], 0, 0, 0);
            }
        }

        // ---- mask + causal + online softmax (in-register) ----
        const bool diag = (jt >= 2 * qt);
        float s[2][4];
        #pragma unroll
        for (int nf = 0; nf < 2; ++nf) {
            float bb_ = mbias[jt * 32 + nf * 16 + l15];
            #pragma unroll
            for (int r = 0; r < 4; ++r) {
                float val = sacc[nf][r] + bb_;
                if (diag) {
                    int gi = qt * 64 + w * 16 + l4 * 4 + r;
                    int gj = jt * 32 + nf * 16 + l15;
                    val = (gj <= gi) ? val : -3e38f;
                }
                s[nf][r] = val;
            }
        }
        float pm[4];
        #pragma unroll
        for (int r = 0; r < 4; ++r) {
            float mx = fmaxf(s[0][r], s[1][r]);
            mx = fmaxf(mx, __shfl_xor(mx, 1));
            mx = fmaxf(mx, __shfl_xor(mx, 2));
            mx = fmaxf(mx, __shfl_xor(mx, 4));
            mx = fmaxf(mx, __shfl_xor(mx, 8));
            pm[r] = mx;
        }
        bool need = false;
        #pragma unroll
        for (int r = 0; r < 4; ++r) need |= (pm[r] - mrow[r] > 8.0f);
        if (__any(need)) {
            #pragma unroll
            for (int r = 0; r < 4; ++r) {
                float mn = fmaxf(mrow[r], pm[r]);
                float corr = __expf(mrow[r] - mn);
                mrow[r] = mn;
                lrow[r] *= corr;
                #pragma unroll
                for (int n = 0; n < 32; ++n) oacc[n][r] *= corr;
            }
        }
        #pragma unroll
        for (int r = 0; r < 4; ++r) {
            float ls = 0.f;
            #pragma unroll
            for (int nf = 0; nf < 2; ++nf) {
                float p = __expf(s[nf][r] - mrow[r]);
                ls += p;
                Pw[w][l4 * 4 + r][nf * 16 + l15] = f2bf(p);
            }
            ls += __shfl_xor(ls, 1);
            ls += __shfl_xor(ls, 2);
            ls += __shfl_xor(ls, 4);
            ls += __shfl_xor(ls, 8);
            lrow[r] += ls;
        }

        // V(jt) published by all waves; Kbuf free (all waves past QK^T(jt)).
        publish_barrier();
        if (jt < jtmax) STAGE_K(jt + 1);

        // ---- PV: O[16 rows][512] += P[16][32] * V[32][512] (V from LDS) ----
        const bf16x8 pa = *(const bf16x8*)&Pw[w][l15][l4 * 8];
        #pragma unroll
        for (int n = 0; n < 32; ++n) {
            const bf16x8 vb_ = *(const bf16x8*)((const char*)VtL + ((n * 16 + l15) << 6) + (l4 << 4));
            oacc[n] = __builtin_amdgcn_mfma_f32_16x16x32_bf16(pa, vb_, oacc[n], 0, 0, 0);
        }
    }

    // ---- epilogue: relu(O / l) ----
    float inv[4];
    #pragma unroll
    for (int r = 0; r < 4; ++r) inv[r] = 1.0f / lrow[r];
    float* op = outp + ((size_t)(b * LL + qt * 64 + w * 16 + l4 * 4)) * DD + l15;
    #pragma unroll
    for (int n = 0; n < 32; ++n)
        #pragma unroll
        for (int r = 0; r < 4; ++r)
            op[(size_t)r * DD + n * 16] = fmaxf(oacc[n][r] * inv[r], 0.f);
    #undef STAGE_K
    #undef STAGE_V
}

extern "C" void kernel_launch(void* const* d_in, const int* in_sizes, int n_in,
                              void* d_out, int out_size, void* d_ws, size_t ws_size,
                              hipStream_t stream) {
    const float* x  = (const float*)d_in[0];
    const float* Wq = (const float*)d_in[1];
    const float* bq = (const float*)d_in[2];
    const float* Wk = (const float*)d_in[3];
    const float* bk = (const float*)d_in[4];
    const float* Wv = (const float*)d_in[5];
    const float* bv = (const float*)d_in[6];
    const int* mask = (const int*)d_in[7];

    unsigned short* qkv = (unsigned short*)d_ws;          // q|k|v bf16
    unsigned short* v   = qkv + 2 * MAT;
    unsigned short* vtp = qkv + 3 * MAT;                  // vt region
    unsigned short* Wb  = vtp;                            // parked, overwritten by vtrans
    unsigned short* xb  = (unsigned short*)d_out;         // x bf16 scratch
    float* out = (float*)d_out;

    cast_x<<<16384, 256, 0, stream>>>(x, xb);
    cast_w<<<768, 256, 0, stream>>>(Wq, Wk, Wv, Wb);
    qkv_proj3<<<dim3(1024, 3), 256, 0, stream>>>(xb, Wb, bq, bk, bv, qkv);
    vtrans<<<dim3(16, 8, 32), 256, 0, stream>>>(v, vtp);
    attn4<<<dim3(512), 256, 0, stream>>>(qkv, vtp, mask, out);
}

// Round 7
// 300.419 us; speedup vs baseline: 1.2989x; 1.0746x over previous
//
#include <hip/hip_runtime.h>
#include <hip/hip_bf16.h>
#include <stdint.h>

#define DM 1024   // d_model
#define DD 512    // d (proj out / head dim)
#define BB 32     // batch
#define LL 1024   // seq len
#define SCALE 0.04419417382415922f  // 1/sqrt(512)
#define MAT ((size_t)BB * LL * DD)  // elems per q/k/v matrix

typedef float f32x4 __attribute__((ext_vector_type(4)));
typedef short bf16x8 __attribute__((ext_vector_type(8)));
typedef short bf16x4 __attribute__((ext_vector_type(4)));

__device__ inline unsigned short f2bf(float f) {
    union { float f; uint32_t u; } v; v.f = f;
    uint32_t r = v.u + 0x7fffu + ((v.u >> 16) & 1u);
    return (unsigned short)(r >> 16);
}

__device__ inline bf16x4 cvt4(f32x4 a, float s) {
    bf16x4 r;
    r[0] = (short)f2bf(a[0] * s);
    r[1] = (short)f2bf(a[1] * s);
    r[2] = (short)f2bf(a[2] * s);
    r[3] = (short)f2bf(a[3] * s);
    return r;
}

#define GLOAD_LDS16(gsrc, ldst) \
    __builtin_amdgcn_global_load_lds((const __attribute__((address_space(1))) unsigned int*)(gsrc), \
        (__attribute__((address_space(3))) unsigned int*)(ldst), 16, 0, 0)

// drain own async loads, then publish across the workgroup
__device__ inline void publish_barrier() {
    asm volatile("s_waitcnt vmcnt(0)" ::: "memory");
    __builtin_amdgcn_sched_barrier(0);
    __builtin_amdgcn_s_barrier();
    __builtin_amdgcn_sched_barrier(0);
}

// ---------------------------------------------------------------------------
// Kernel 0a: cast x fp32 -> bf16 (dest: d_out reused as scratch; dead by attn)
// ---------------------------------------------------------------------------
__global__ __launch_bounds__(256) void cast_x(const float* __restrict__ x,
                                              unsigned short* __restrict__ xb)
{
    size_t idx = (size_t)blockIdx.x * 256 + threadIdx.x;
    size_t base = idx * 8;
    f32x4 a = *(const f32x4*)(x + base);
    f32x4 b = *(const f32x4*)(x + base + 4);
    bf16x4 lo = cvt4(a, 1.0f), hi = cvt4(b, 1.0f);
    bf16x8 o = {lo[0], lo[1], lo[2], lo[3], hi[0], hi[1], hi[2], hi[3]};
    *(bf16x8*)(xb + base) = o;
}

// ---------------------------------------------------------------------------
// Kernel 0b: cast Wq/Wk/Wv fp32 -> bf16 (Wq pre-scaled by 1/sqrt(D))
// ---------------------------------------------------------------------------
__global__ __launch_bounds__(256) void cast_w(const float* __restrict__ Wq,
                                              const float* __restrict__ Wk,
                                              const float* __restrict__ Wv,
                                              unsigned short* __restrict__ Wb)
{
    size_t idx = (size_t)blockIdx.x * 256 + threadIdx.x;   // 0..196607
    int o = (int)(idx >> 16);
    size_t rem = idx & 65535;
    const float* W = (o == 0) ? Wq : (o == 1) ? Wk : Wv;
    float s = (o == 0) ? SCALE : 1.0f;
    size_t base = rem * 8;
    f32x4 a = *(const f32x4*)(W + base);
    f32x4 b = *(const f32x4*)(W + base + 4);
    bf16x4 lo = cvt4(a, s), hi = cvt4(b, s);
    bf16x8 out = {lo[0], lo[1], lo[2], lo[3], hi[0], hi[1], hi[2], hi[3]};
    *(bf16x8*)(Wb + (size_t)o * 524288 + base) = out;
}

// ---------------------------------------------------------------------------
// Kernel 1: q/k/v projection v3 (unchanged from round 4; 137 us, 0 conflicts).
// ---------------------------------------------------------------------------
__global__ __launch_bounds__(256, 2) void qkv_proj3(
    const unsigned short* __restrict__ xb,   // [32768][1024] bf16
    const unsigned short* __restrict__ Wb,   // [3][512][1024] bf16 (q pre-scaled)
    const float* __restrict__ bq, const float* __restrict__ bk, const float* __restrict__ bv,
    unsigned short* __restrict__ qkv)
{
    __shared__ __align__(16) unsigned short At[2][8192];  // [buf][128 rows][128 B]
    __shared__ __align__(16) unsigned short Bt[2][8192];  // 64 KB total

    const int o = blockIdx.y;
    const float* bias = (o == 0) ? bq : (o == 1) ? bk : bv;
    const float wscale = (o == 0) ? SCALE : 1.0f;
    const unsigned short* W = Wb + (size_t)o * 524288;
    unsigned short* out = qkv + (size_t)o * MAT;

    int wg = blockIdx.x;
    wg = (wg & 7) * 128 + (wg >> 3);           // XCD swizzle (bijective, 1024 = 8*128)
    const int rowbase = (wg >> 2) * 128;
    const int colbase = (wg & 3) * 128;

    const int tid  = threadIdx.x;
    const int lane = tid & 63;
    const int w    = tid >> 6;
    const int wr   = (w >> 1) * 64;
    const int wc   = (w & 1) * 64;
    const int l15  = lane & 15, l4 = lane >> 4;

    const int r8   = lane >> 3;                // row within 8-row group
    const int swch = (lane & 7) ^ r8;          // pre-swizzled source chunk

    const char* xpanel = (const char*)(xb + (size_t)rowbase * DM);
    const char* wpanel = (const char*)(W  + (size_t)colbase * DM);

    f32x4 acc[4][4];
    #pragma unroll
    for (int i = 0; i < 4; ++i)
        #pragma unroll
        for (int j = 0; j < 4; ++j)
            acc[i][j] = (f32x4){0.f, 0.f, 0.f, 0.f};

    #define STAGE_AB(KK, BUF) do {                                               \
        _Pragma("unroll")                                                        \
        for (int i2 = 0; i2 < 4; ++i2) {                                         \
            int grp = i2 * 4 + w;                                                \
            size_t rowoff = (size_t)(grp * 8 + r8) * 2048 + (KK) * 2 + swch * 16;\
            GLOAD_LDS16(xpanel + rowoff, (char*)&At[BUF][0] + grp * 1024);       \
            GLOAD_LDS16(wpanel + rowoff, (char*)&Bt[BUF][0] + grp * 1024);       \
        }                                                                        \
    } while (0)

    STAGE_AB(0, 0);
    __syncthreads();

    for (int t = 0; t < 16; ++t) {
        const int cur = t & 1;
        if (t < 15) STAGE_AB((t + 1) * 64, cur ^ 1);

        const char* Ab = (const char*)&At[cur][0];
        const char* Bb = (const char*)&Bt[cur][0];
        #pragma unroll
        for (int ks = 0; ks < 2; ++ks) {
            bf16x8 af[4], bf_[4];
            const int ch = (ks * 4 + l4) ^ (l15 & 7);
            #pragma unroll
            for (int m = 0; m < 4; ++m) {
                int row = wr + m * 16 + l15;
                af[m] = *(const bf16x8*)(Ab + row * 128 + (ch << 4));
            }
            #pragma unroll
            for (int n = 0; n < 4; ++n) {
                int row = wc + n * 16 + l15;
                bf_[n] = *(const bf16x8*)(Bb + row * 128 + (ch << 4));
            }
            #pragma unroll
            for (int n = 0; n < 4; ++n)
                #pragma unroll
                for (int m = 0; m < 4; ++m)
                    acc[m][n] = __builtin_amdgcn_mfma_f32_16x16x32_bf16(af[m], bf_[n], acc[m][n], 0, 0, 0);
        }

        if (t < 15) publish_barrier();
    }
    #undef STAGE_AB

    #pragma unroll
    for (int n = 0; n < 4; ++n) {
        int col = colbase + wc + n * 16 + l15;
        float bv_ = bias[col] * wscale;
        #pragma unroll
        for (int m = 0; m < 4; ++m) {
            int row0 = rowbase + wr + m * 16 + l4 * 4;
            #pragma unroll
            for (int r = 0; r < 4; ++r)
                out[(size_t)(row0 + r) * DD + col] = f2bf(acc[m][n][r] + bv_);
        }
    }
}

// ---------------------------------------------------------------------------
// Kernel 2: V transpose.  v[b][l][d] -> vt[b][d][l]  (bf16)
// ---------------------------------------------------------------------------
__global__ __launch_bounds__(256) void vtrans(const unsigned short* __restrict__ v,
                                              unsigned short* __restrict__ vt)
{
    __shared__ unsigned short T[64][72];
    const int lt = blockIdx.x, dt = blockIdx.y, b = blockIdx.z;
    const int t = threadIdx.x;
    const unsigned short* src = v + ((size_t)(b * LL + lt * 64)) * DD + dt * 64;
    #pragma unroll
    for (int it = 0; it < 2; ++it) {
        int r  = (t >> 3) + it * 32;
        int c0 = (t & 7) * 8;
        bf16x8 x = *(const bf16x8*)(src + (size_t)r * DD + c0);
        *(bf16x4*)&T[r][c0]     = (bf16x4){x[0], x[1], x[2], x[3]};
        *(bf16x4*)&T[r][c0 + 4] = (bf16x4){x[4], x[5], x[6], x[7]};
    }
    __syncthreads();
    unsigned short* dst = vt + ((size_t)(b * DD + dt * 64)) * LL + lt * 64;
    #pragma unroll
    for (int it = 0; it < 2; ++it) {
        int d  = (t >> 3) + it * 32;
        int c0 = (t & 7) * 8;
        bf16x8 o;
        #pragma unroll
        for (int e = 0; e < 8; ++e) o[e] = T[c0 + e][d];
        *(bf16x8*)(dst + (size_t)d * LL + c0) = o;
    }
}

// ---------------------------------------------------------------------------
// Kernel 3: flash attention v5 — attn3's dbuf 1-barrier/tile schedule with
// 8 waves (512 thr) and split-D PV to break the unified-register occupancy
// ceiling. gfx950 unified VGPR+AGPR pool = 512/SIMD; attn3/4's ~352/wave
// capped residency at 1 wave/SIMD (Occ 9%). Here wave (wm,wd): wm = 16 own
// q-rows, full QK^T+softmax (duplicated across the wd pair — MFMA util was
// 8.5%, duplication is free); wd = 256-wide d-half of PV -> oacc 64 AGPR,
// ~200 unified regs/wave -> 2 waves/SIMD from one 8-wave block.
// ---------------------------------------------------------------------------
__global__ __launch_bounds__(512) void attn5(
    const unsigned short* __restrict__ qkv,
    const unsigned short* __restrict__ vt,
    const int* __restrict__ mask,
    float* __restrict__ outp)
{
    __shared__ __align__(16) unsigned short KtL[2][16384];  // 2 x [32 keys][512 d] = 64 KB
    __shared__ __align__(16) unsigned short VtL[2][16384];  // 2 x [512 d][32 keys] = 64 KB
    __shared__ __align__(16) unsigned short Pw[8][16][36];  // 9 KB (per-wave P copy)
    __shared__ float mbias[1024];                           // 4 KB; total 144,384 B

    const int bx = blockIdx.x;
    const int h = bx >> 8, i = bx & 255;
    const int b = i & 31;
    const int qtx = (i >> 5) & 7;
    const int qt = h ? qtx : 15 - qtx;   // heavy+light pairing across rounds

    const int tid = threadIdx.x, lane = tid & 63, w = tid >> 6;
    const int wm = w & 3;        // q-row group (16 rows)
    const int wd = w >> 2;       // d-half for PV (0/1)
    const int l15 = lane & 15, l4 = lane >> 4;
    const int lsw = lane * 16;

    const unsigned short* q = qkv;
    const unsigned short* k = qkv + MAT;
    const char* kb  = (const char*)k + ((size_t)b * LL) * DD * 2;   // row = 1024 B
    const char* vtb = (const char*)vt + ((size_t)b * DD) * LL * 2;  // row = 2048 B

    {
        const int* mp = mask + b * LL;
        #pragma unroll
        for (int j = 0; j < 2; ++j)
            mbias[tid * 2 + j] = mp[tid * 2 + j] ? 0.0f : -1e30f;
    }

    // persistent Q A-frags, full D (64 VGPR)
    bf16x8 qf[16];
    {
        const unsigned short* qp = q + ((size_t)(b * LL + qt * 64 + wm * 16 + l15)) * DD + l4 * 8;
        #pragma unroll
        for (int ks = 0; ks < 16; ++ks)
            qf[ks] = *(const bf16x8*)(qp + ks * 32);
    }

    f32x4 oacc[16];   // 256-wide d-half -> 64 AGPR
    #pragma unroll
    for (int n = 0; n < 16; ++n) oacc[n] = (f32x4){0.f, 0.f, 0.f, 0.f};
    float mrow[4] = {-1e30f, -1e30f, -1e30f, -1e30f};
    float lrow[4] = {0.f, 0.f, 0.f, 0.f};

    const int jtmax = 2 * qt + 1;

    // 8 waves: K 4 rows/wave, V 4 gload/wave
    #define STAGE_KV(JT, BUF) do {                                              \
        const char* kt = kb + ((size_t)(JT) << 15);                             \
        char* ldsK = (char*)&KtL[(BUF)][0];                                     \
        _Pragma("unroll")                                                       \
        for (int i2 = 0; i2 < 4; ++i2) {                                        \
            int row = i2 * 8 + w;                                               \
            GLOAD_LDS16(kt + (row << 10) + (lsw ^ ((row & 7) << 4)),            \
                        ldsK + (row << 10));                                    \
        }                                                                       \
        const char* vtj = vtb + ((size_t)(JT) << 6);                            \
        char* ldsV = (char*)&VtL[(BUF)][0];                                     \
        _Pragma("unroll")                                                       \
        for (int i2 = 0; i2 < 4; ++i2) {                                        \
            int c0 = i2 * 512 + w * 64;                                         \
            int c  = c0 + lane;                                                 \
            GLOAD_LDS16(vtj + ((size_t)(c >> 2) << 11) + ((c & 3) << 4),        \
                        ldsV + c0 * 16);                                        \
        }                                                                       \
    } while (0)

    STAGE_KV(0, 0);
    __syncthreads();   // drains mbias ds_writes (lgkm) + stage(0) (vm), publishes

    const int swz = (l15 & 7) << 4;

    for (int jt = 0; jt <= jtmax; ++jt) {
        const int cur = jt & 1;
        if (jt < jtmax) STAGE_KV(jt + 1, cur ^ 1);

        // ---- QK^T: S[16 own rows][32 keys] from swizzled K LDS (full D) ----
        const char* Kc = (const char*)&KtL[cur][0];
        f32x4 sacc[2];
        sacc[0] = (f32x4){0.f, 0.f, 0.f, 0.f};
        sacc[1] = (f32x4){0.f, 0.f, 0.f, 0.f};
        #pragma unroll
        for (int ks = 0; ks < 16; ++ks) {
            int coloff = ((ks << 6) + (l4 << 4)) ^ swz;
            #pragma unroll
            for (int nf = 0; nf < 2; ++nf) {
                const bf16x8 kf = *(const bf16x8*)(Kc + ((nf * 16 + l15) << 10) + coloff);
                sacc[nf] = __builtin_amdgcn_mfma_f32_16x16x32_bf16(qf[ks], kf, sacc[nf], 0, 0, 0);
            }
        }

        // ---- mask + causal + online softmax (in-register, dup across wd) ----
        const bool diag = (jt >= 2 * qt);
        float s[2][4];
        #pragma unroll
        for (int nf = 0; nf < 2; ++nf) {
            float bb_ = mbias[jt * 32 + nf * 16 + l15];
            #pragma unroll
            for (int r = 0; r < 4; ++r) {
                float val = sacc[nf][r] + bb_;
                if (diag) {
                    int gi = qt * 64 + wm * 16 + l4 * 4 + r;
                    int gj = jt * 32 + nf * 16 + l15;
                    val = (gj <= gi) ? val : -3e38f;
                }
                s[nf][r] = val;
            }
        }
        float pm[4];
        #pragma unroll
        for (int r = 0; r < 4; ++r) {
            float mx = fmaxf(s[0][r], s[1][r]);
            mx = fmaxf(mx, __shfl_xor(mx, 1));
            mx = fmaxf(mx, __shfl_xor(mx, 2));
            mx = fmaxf(mx, __shfl_xor(mx, 4));
            mx = fmaxf(mx, __shfl_xor(mx, 8));
            pm[r] = mx;
        }
        bool need = false;
        #pragma unroll
        for (int r = 0; r < 4; ++r) need |= (pm[r] - mrow[r] > 8.0f);
        if (__any(need)) {
            #pragma unroll
            for (int r = 0; r < 4; ++r) {
                float mn = fmaxf(mrow[r], pm[r]);
                float corr = __expf(mrow[r] - mn);
                mrow[r] = mn;
                lrow[r] *= corr;
                #pragma unroll
                for (int n = 0; n < 16; ++n) oacc[n][r] *= corr;
            }
        }
        #pragma unroll
        for (int r = 0; r < 4; ++r) {
            float ls = 0.f;
            #pragma unroll
            for (int nf = 0; nf < 2; ++nf) {
                float p = __expf(s[nf][r] - mrow[r]);
                ls += p;
                Pw[w][l4 * 4 + r][nf * 16 + l15] = f2bf(p);
            }
            ls += __shfl_xor(ls, 1);
            ls += __shfl_xor(ls, 2);
            ls += __shfl_xor(ls, 4);
            ls += __shfl_xor(ls, 8);
            lrow[r] += ls;
        }

        // ---- PV: O[16 rows][256-wide half] += P[16][32] * V[32][d-half] ----
        const bf16x8 pa = *(const bf16x8*)&Pw[w][l15][l4 * 8];
        const char* Vc = (const char*)&VtL[cur][0];
        #pragma unroll
        for (int n = 0; n < 16; ++n) {
            int drow = wd * 256 + n * 16 + l15;
            const bf16x8 vb_ = *(const bf16x8*)(Vc + (drow << 6) + (l4 << 4));
            oacc[n] = __builtin_amdgcn_mfma_f32_16x16x32_bf16(pa, vb_, oacc[n], 0, 0, 0);
        }

        if (jt < jtmax) publish_barrier();   // stage(jt+1) drained; buf[cur] consumed
    }

    // ---- epilogue: relu(O / l) on own d-half ----
    float inv[4];
    #pragma unroll
    for (int r = 0; r < 4; ++r) inv[r] = 1.0f / lrow[r];
    float* op = outp + ((size_t)(b * LL + qt * 64 + wm * 16 + l4 * 4)) * DD + wd * 256 + l15;
    #pragma unroll
    for (int n = 0; n < 16; ++n)
        #pragma unroll
        for (int r = 0; r < 4; ++r)
            op[(size_t)r * DD + n * 16] = fmaxf(oacc[n][r] * inv[r], 0.f);
    #undef STAGE_KV
}

extern "C" void kernel_launch(void* const* d_in, const int* in_sizes, int n_in,
                              void* d_out, int out_size, void* d_ws, size_t ws_size,
                              hipStream_t stream) {
    const float* x  = (const float*)d_in[0];
    const float* Wq = (const float*)d_in[1];
    const float* bq = (const float*)d_in[2];
    const float* Wk = (const float*)d_in[3];
    const float* bk = (const float*)d_in[4];
    const float* Wv = (const float*)d_in[5];
    const float* bv = (const float*)d_in[6];
    const int* mask = (const int*)d_in[7];

    unsigned short* qkv = (unsigned short*)d_ws;          // q|k|v bf16
    unsigned short* v   = qkv + 2 * MAT;
    unsigned short* vtp = qkv + 3 * MAT;                  // vt region
    unsigned short* Wb  = vtp;                            // parked, overwritten by vtrans
    unsigned short* xb  = (unsigned short*)d_out;         // x bf16 scratch
    float* out = (float*)d_out;

    cast_x<<<16384, 256, 0, stream>>>(x, xb);
    cast_w<<<768, 256, 0, stream>>>(Wq, Wk, Wv, Wb);
    qkv_proj3<<<dim3(1024, 3), 256, 0, stream>>>(xb, Wb, bq, bk, bv, qkv);
    vtrans<<<dim3(16, 8, 32), 256, 0, stream>>>(v, vtp);
    attn5<<<dim3(512), 512, 0, stream>>>(qkv, vtp, mask, out);
}

// Round 8
// 278.611 us; speedup vs baseline: 1.4006x; 1.0783x over previous
//
#include <hip/hip_runtime.h>
#include <hip/hip_bf16.h>
#include <stdint.h>

#define DM 1024   // d_model
#define DD 512    // d (proj out / head dim)
#define BB 32     // batch
#define LL 1024   // seq len
#define SCALE 0.04419417382415922f  // 1/sqrt(512)
#define MAT ((size_t)BB * LL * DD)  // elems per q/k/v matrix

typedef float f32x4 __attribute__((ext_vector_type(4)));
typedef short bf16x8 __attribute__((ext_vector_type(8)));
typedef short bf16x4 __attribute__((ext_vector_type(4)));

__device__ inline unsigned short f2bf(float f) {
    union { float f; uint32_t u; } v; v.f = f;
    uint32_t r = v.u + 0x7fffu + ((v.u >> 16) & 1u);
    return (unsigned short)(r >> 16);
}

__device__ inline bf16x4 cvt4(f32x4 a, float s) {
    bf16x4 r;
    r[0] = (short)f2bf(a[0] * s);
    r[1] = (short)f2bf(a[1] * s);
    r[2] = (short)f2bf(a[2] * s);
    r[3] = (short)f2bf(a[3] * s);
    return r;
}

#define GLOAD_LDS16(gsrc, ldst) \
    __builtin_amdgcn_global_load_lds((const __attribute__((address_space(1))) unsigned int*)(gsrc), \
        (__attribute__((address_space(3))) unsigned int*)(ldst), 16, 0, 0)

// full-drain barrier (attn3's per-tile publish)
__device__ inline void tile_barrier() {
    asm volatile("s_waitcnt vmcnt(0)" ::: "memory");
    __builtin_amdgcn_sched_barrier(0);
    __builtin_amdgcn_s_barrier();
    __builtin_amdgcn_sched_barrier(0);
}

// counted-vmcnt phase gates (T4: never drain to 0 in steady state)
__device__ inline void gate6() {
    asm volatile("s_waitcnt vmcnt(6)" ::: "memory");
    __builtin_amdgcn_sched_barrier(0);
    __builtin_amdgcn_s_barrier();
    __builtin_amdgcn_sched_barrier(0);
}
__device__ inline void gate4() {
    asm volatile("s_waitcnt vmcnt(4)" ::: "memory");
    __builtin_amdgcn_sched_barrier(0);
    __builtin_amdgcn_s_barrier();
    __builtin_amdgcn_sched_barrier(0);
}
__device__ inline void gate2() {
    asm volatile("s_waitcnt vmcnt(2)" ::: "memory");
    __builtin_amdgcn_sched_barrier(0);
    __builtin_amdgcn_s_barrier();
    __builtin_amdgcn_sched_barrier(0);
}
__device__ inline void gate0() {
    asm volatile("s_waitcnt vmcnt(0)" ::: "memory");
    __builtin_amdgcn_sched_barrier(0);
    __builtin_amdgcn_s_barrier();
    __builtin_amdgcn_sched_barrier(0);
}
__device__ inline void gateB() {
    __builtin_amdgcn_sched_barrier(0);
    __builtin_amdgcn_s_barrier();
    __builtin_amdgcn_sched_barrier(0);
}

// ---------------------------------------------------------------------------
// Kernel 0a: cast x fp32 -> bf16 (dest: d_out reused as scratch; dead by attn)
// ---------------------------------------------------------------------------
__global__ __launch_bounds__(256) void cast_x(const float* __restrict__ x,
                                              unsigned short* __restrict__ xb)
{
    size_t idx = (size_t)blockIdx.x * 256 + threadIdx.x;
    size_t base = idx * 8;
    f32x4 a = *(const f32x4*)(x + base);
    f32x4 b = *(const f32x4*)(x + base + 4);
    bf16x4 lo = cvt4(a, 1.0f), hi = cvt4(b, 1.0f);
    bf16x8 o = {lo[0], lo[1], lo[2], lo[3], hi[0], hi[1], hi[2], hi[3]};
    *(bf16x8*)(xb + base) = o;
}

// ---------------------------------------------------------------------------
// Kernel 0b: cast Wq/Wk/Wv fp32 -> bf16 (Wq pre-scaled by 1/sqrt(D))
// ---------------------------------------------------------------------------
__global__ __launch_bounds__(256) void cast_w(const float* __restrict__ Wq,
                                              const float* __restrict__ Wk,
                                              const float* __restrict__ Wv,
                                              unsigned short* __restrict__ Wb)
{
    size_t idx = (size_t)blockIdx.x * 256 + threadIdx.x;   // 0..196607
    int o = (int)(idx >> 16);
    size_t rem = idx & 65535;
    const float* W = (o == 0) ? Wq : (o == 1) ? Wk : Wv;
    float s = (o == 0) ? SCALE : 1.0f;
    size_t base = rem * 8;
    f32x4 a = *(const f32x4*)(W + base);
    f32x4 b = *(const f32x4*)(W + base + 4);
    bf16x4 lo = cvt4(a, s), hi = cvt4(b, s);
    bf16x8 out = {lo[0], lo[1], lo[2], lo[3], hi[0], hi[1], hi[2], hi[3]};
    *(bf16x8*)(Wb + (size_t)o * 524288 + base) = out;
}

// ---------------------------------------------------------------------------
// Kernel 1: q/k/v projection v4 — 8-phase 256x256 tile, BK=64, counted vmcnt.
// 8 waves (512 thr). Wave w (wm=w>>2, wn=w&3) output 128x64 SPLIT across
// halves: rows {wm*64..+64} of A-half0 AND A-half1; cols {wn*32..+32} of
// B-half0 AND B-half1. Per K-tile 4 phases consume (A0,B0),(A0,B1),(A1,B0),
// (A1,B1); halves of t+1 staged one-per-phase in order A0,B0,B1,A1 => every
// half has >=3-phase lookahead. Gate = s_waitcnt vmcnt(6)+barrier per phase
// (epilogue 4/2/0) — stage loads stay in flight across barriers, no full
// drain. LDS 128KB (2buf x 2half x 16KB x {A,B}); proj3's proven 0-conflict
// XOR stage/read scheme per half-tile slot.
// ---------------------------------------------------------------------------
__global__ __launch_bounds__(512, 2) void qkv_proj4(
    const unsigned short* __restrict__ xb,   // [32768][1024] bf16
    const unsigned short* __restrict__ Wb,   // [3][512][1024] bf16 (q pre-scaled)
    const float* __restrict__ bq, const float* __restrict__ bk, const float* __restrict__ bv,
    unsigned short* __restrict__ qkv)
{
    __shared__ __align__(16) unsigned short AL[2][2][8192];  // [buf][half][128 rows x 128B]
    __shared__ __align__(16) unsigned short BL[2][2][8192];  // 128 KB total

    const int o = blockIdx.y;
    const float* bias = (o == 0) ? bq : (o == 1) ? bk : bv;
    const float wscale = (o == 0) ? SCALE : 1.0f;
    const unsigned short* W = Wb + (size_t)o * 524288;
    unsigned short* out = qkv + (size_t)o * MAT;

    int wg = blockIdx.x;                    // 256 blocks: XCD swizzle (8 x 32, bijective)
    wg = (wg & 7) * 32 + (wg >> 3);
    const int mt = wg >> 1, nt = wg & 1;
    const int rowbase = mt * 256;
    const int colbase = nt * 256;

    const int tid  = threadIdx.x;
    const int lane = tid & 63;
    const int w    = tid >> 6;              // 0..7
    const int wm   = w >> 2;                // 0..1 (row 64-group within each half)
    const int wn   = w & 3;                 // 0..3 (col 32-group within each half)
    const int l15  = lane & 15, l4 = lane >> 4;
    const int rxor = l15 & 7;

    const int r8   = lane >> 3;             // staging: row within 8-row group
    const int swch = (lane & 7) ^ r8;       // pre-swizzled source chunk

    const char* xpanel = (const char*)(xb + (size_t)rowbase * DM);
    const char* wpanel = (const char*)(W  + (size_t)colbase * DM);

    // stage one 16KB half-tile (128 rows x 128B): 2 gload_lds per thread
    #define STAGE_HALF(panel, T, H, slot) do {                                   \
        _Pragma("unroll")                                                        \
        for (int i2 = 0; i2 < 2; ++i2) {                                         \
            int grp = i2 * 8 + w;                                                \
            GLOAD_LDS16((panel) + ((size_t)((H) * 128 + grp * 8 + r8) * 2048)    \
                            + (size_t)(T) * 128 + swch * 16,                     \
                        (char*)(slot) + grp * 1024);                             \
        }                                                                        \
    } while (0)

    #define RDA(base, mf4, ks) (*(const bf16x8*)((base) + (wm * 64 + (mf4) * 16 + l15) * 128 \
                            + ((((ks) * 4 + l4) ^ rxor) << 4)))
    #define RDB(base, nfl, ks) (*(const bf16x8*)((base) + (wn * 32 + (nfl) * 16 + l15) * 128 \
                            + ((((ks) * 4 + l4) ^ rxor) << 4)))

    f32x4 acc[8][4];
    #pragma unroll
    for (int i = 0; i < 8; ++i)
        #pragma unroll
        for (int j = 0; j < 4; ++j)
            acc[i][j] = (f32x4){0.f, 0.f, 0.f, 0.f};

    bf16x8 aF[4][2], bF[4][2];

    // prologue: stage tile 0's four halves in consumption-stagger order
    STAGE_HALF(xpanel, 0, 0, &AL[0][0][0]);   // A0
    STAGE_HALF(wpanel, 0, 0, &BL[0][0][0]);   // B0
    STAGE_HALF(wpanel, 0, 1, &BL[0][1][0]);   // B1
    STAGE_HALF(xpanel, 0, 1, &AL[0][1][0]);   // A1

    for (int t = 0; t < 16; ++t) {
        const int c = t & 1, cn = c ^ 1;
        const char* A0b = (const char*)&AL[c][0][0];
        const char* A1b = (const char*)&AL[c][1][0];
        const char* B0b = (const char*)&BL[c][0][0];
        const char* B1b = (const char*)&BL[c][1][0];
        const bool st = (t < 15);

        // ---- phase 0: (A0,B0) ----
        if (st) { STAGE_HALF(xpanel, t + 1, 0, &AL[cn][0][0]); gate6(); } else gate4();
        #pragma unroll
        for (int ks = 0; ks < 2; ++ks) {
            #pragma unroll
            for (int mf = 0; mf < 4; ++mf) aF[mf][ks] = RDA(A0b, mf, ks);
            bF[0][ks] = RDB(B0b, 0, ks);
            bF[1][ks] = RDB(B0b, 1, ks);
        }
        #pragma unroll
        for (int ks = 0; ks < 2; ++ks)
            #pragma unroll
            for (int nf = 0; nf < 2; ++nf)
                #pragma unroll
                for (int mf = 0; mf < 4; ++mf)
                    acc[mf][nf] = __builtin_amdgcn_mfma_f32_16x16x32_bf16(aF[mf][ks], bF[nf][ks], acc[mf][nf], 0, 0, 0);

        // ---- phase 1: (A0,B1) ----
        if (st) { STAGE_HALF(wpanel, t + 1, 0, &BL[cn][0][0]); gate6(); } else gate2();
        #pragma unroll
        for (int ks = 0; ks < 2; ++ks) {
            bF[2][ks] = RDB(B1b, 0, ks);
            bF[3][ks] = RDB(B1b, 1, ks);
        }
        #pragma unroll
        for (int ks = 0; ks < 2; ++ks)
            #pragma unroll
            for (int nf = 0; nf < 2; ++nf)
                #pragma unroll
                for (int mf = 0; mf < 4; ++mf)
                    acc[mf][2 + nf] = __builtin_amdgcn_mfma_f32_16x16x32_bf16(aF[mf][ks], bF[2 + nf][ks], acc[mf][2 + nf], 0, 0, 0);

        // ---- phase 2: (A1,B0) ----
        if (st) { STAGE_HALF(wpanel, t + 1, 1, &BL[cn][1][0]); gate6(); } else gate0();
        #pragma unroll
        for (int ks = 0; ks < 2; ++ks)
            #pragma unroll
            for (int mf = 0; mf < 4; ++mf) aF[mf][ks] = RDA(A1b, mf, ks);
        #pragma unroll
        for (int ks = 0; ks < 2; ++ks)
            #pragma unroll
            for (int nf = 0; nf < 2; ++nf)
                #pragma unroll
                for (int mf = 0; mf < 4; ++mf)
                    acc[4 + mf][nf] = __builtin_amdgcn_mfma_f32_16x16x32_bf16(aF[mf][ks], bF[nf][ks], acc[4 + mf][nf], 0, 0, 0);

        // ---- phase 3: (A1,B1) ----
        if (st) STAGE_HALF(xpanel, t + 1, 1, &AL[cn][1][0]);
        gateB();
        #pragma unroll
        for (int ks = 0; ks < 2; ++ks)
            #pragma unroll
            for (int nf = 0; nf < 2; ++nf)
                #pragma unroll
                for (int mf = 0; mf < 4; ++mf)
                    acc[4 + mf][2 + nf] = __builtin_amdgcn_mfma_f32_16x16x32_bf16(aF[mf][ks], bF[2 + nf][ks], acc[4 + mf][2 + nf], 0, 0, 0);
    }
    #undef STAGE_HALF
    #undef RDA
    #undef RDB

    // epilogue: + bias, cvt bf16, store
    #pragma unroll
    for (int nf = 0; nf < 4; ++nf) {
        int col = colbase + ((nf < 2) ? wn * 32 + nf * 16 : 128 + wn * 32 + (nf - 2) * 16) + l15;
        float bv_ = bias[col] * wscale;
        #pragma unroll
        for (int mf = 0; mf < 8; ++mf) {
            int row0 = rowbase + ((mf < 4) ? wm * 64 + mf * 16 : 128 + wm * 64 + (mf - 4) * 16) + l4 * 4;
            #pragma unroll
            for (int r = 0; r < 4; ++r)
                out[(size_t)(row0 + r) * DD + col] = f2bf(acc[mf][nf][r] + bv_);
        }
    }
}

// ---------------------------------------------------------------------------
// Kernel 2: V transpose.  v[b][l][d] -> vt[b][d][l]  (bf16)
// ---------------------------------------------------------------------------
__global__ __launch_bounds__(256) void vtrans(const unsigned short* __restrict__ v,
                                              unsigned short* __restrict__ vt)
{
    __shared__ unsigned short T[64][72];
    const int lt = blockIdx.x, dt = blockIdx.y, b = blockIdx.z;
    const int t = threadIdx.x;
    const unsigned short* src = v + ((size_t)(b * LL + lt * 64)) * DD + dt * 64;
    #pragma unroll
    for (int it = 0; it < 2; ++it) {
        int r  = (t >> 3) + it * 32;
        int c0 = (t & 7) * 8;
        bf16x8 x = *(const bf16x8*)(src + (size_t)r * DD + c0);
        *(bf16x4*)&T[r][c0]     = (bf16x4){x[0], x[1], x[2], x[3]};
        *(bf16x4*)&T[r][c0 + 4] = (bf16x4){x[4], x[5], x[6], x[7]};
    }
    __syncthreads();
    unsigned short* dst = vt + ((size_t)(b * DD + dt * 64)) * LL + lt * 64;
    #pragma unroll
    for (int it = 0; it < 2; ++it) {
        int d  = (t >> 3) + it * 32;
        int c0 = (t & 7) * 8;
        bf16x8 o;
        #pragma unroll
        for (int e = 0; e < 8; ++e) o[e] = T[c0 + e][d];
        *(bf16x8*)(dst + (size_t)d * LL + c0) = o;
    }
}

// ---------------------------------------------------------------------------
// Kernel 3: flash attention v3 (round-4 version, verbatim — 137 us).
// ---------------------------------------------------------------------------
__global__ __launch_bounds__(256, 1) void attn3(
    const unsigned short* __restrict__ qkv,
    const unsigned short* __restrict__ vt,
    const int* __restrict__ mask,
    float* __restrict__ outp)
{
    __shared__ __align__(16) unsigned short KtL[2][16384];  // 2 x [32 keys][512 d]
    __shared__ __align__(16) unsigned short VtL[2][16384];  // 2 x [512 d][32 keys]
    __shared__ __align__(16) unsigned short Pw[4][16][36];
    __shared__ float mbias[1024];

    const int bx = blockIdx.x;
    const int h = bx >> 8, i = bx & 255;
    const int b = i & 31;
    const int qtx = (i >> 5) & 7;
    const int qt = h ? qtx : 15 - qtx;

    const int tid = threadIdx.x, lane = tid & 63, w = tid >> 6;
    const int l15 = lane & 15, l4 = lane >> 4;
    const int lsw = lane * 16;

    const unsigned short* q = qkv;
    const unsigned short* k = qkv + MAT;
    const char* kb  = (const char*)k + ((size_t)b * LL) * DD * 2;
    const char* vtb = (const char*)vt + ((size_t)b * DD) * LL * 2;

    {
        const int* mp = mask + b * LL;
        #pragma unroll
        for (int j = 0; j < 4; ++j)
            mbias[tid * 4 + j] = mp[tid * 4 + j] ? 0.0f : -1e30f;
    }

    bf16x8 qf[16];
    {
        const unsigned short* qp = q + ((size_t)(b * LL + qt * 64 + w * 16 + l15)) * DD + l4 * 8;
        #pragma unroll
        for (int ks = 0; ks < 16; ++ks)
            qf[ks] = *(const bf16x8*)(qp + ks * 32);
    }

    f32x4 oacc[32];
    #pragma unroll
    for (int n = 0; n < 32; ++n) oacc[n] = (f32x4){0.f, 0.f, 0.f, 0.f};
    float mrow[4] = {-1e30f, -1e30f, -1e30f, -1e30f};
    float lrow[4] = {0.f, 0.f, 0.f, 0.f};

    const int jtmax = 2 * qt + 1;

    #define STAGE_KV(JT, BUF) do {                                              \
        const char* kt = kb + ((size_t)(JT) << 15);                             \
        char* ldsK = (char*)&KtL[(BUF)][0];                                     \
        _Pragma("unroll")                                                       \
        for (int i2 = 0; i2 < 8; ++i2) {                                        \
            int row = i2 * 4 + w;                                               \
            GLOAD_LDS16(kt + (row << 10) + (lsw ^ ((row & 7) << 4)),            \
                        ldsK + (row << 10));                                    \
        }                                                                       \
        const char* vtj = vtb + ((size_t)(JT) << 6);                            \
        char* ldsV = (char*)&VtL[(BUF)][0];                                     \
        _Pragma("unroll")                                                       \
        for (int i2 = 0; i2 < 8; ++i2) {                                        \
            int c0 = i2 * 256 + w * 64;                                         \
            int c  = c0 + lane;                                                 \
            GLOAD_LDS16(vtj + ((size_t)(c >> 2) << 11) + ((c & 3) << 4),        \
                        ldsV + c0 * 16);                                        \
        }                                                                       \
    } while (0)

    STAGE_KV(0, 0);
    __syncthreads();

    const int swz = (l15 & 7) << 4;

    for (int jt = 0; jt <= jtmax; ++jt) {
        const int cur = jt & 1;
        if (jt < jtmax) STAGE_KV(jt + 1, cur ^ 1);

        const char* Kc = (const char*)&KtL[cur][0];
        f32x4 sacc[2];
        sacc[0] = (f32x4){0.f, 0.f, 0.f, 0.f};
        sacc[1] = (f32x4){0.f, 0.f, 0.f, 0.f};
        #pragma unroll
        for (int ks = 0; ks < 16; ++ks) {
            int coloff = ((ks << 6) + (l4 << 4)) ^ swz;
            #pragma unroll
            for (int nf = 0; nf < 2; ++nf) {
                const bf16x8 kf = *(const bf16x8*)(Kc + ((nf * 16 + l15) << 10) + coloff);
                sacc[nf] = __builtin_amdgcn_mfma_f32_16x16x32_bf16(qf[ks], kf, sacc[nf], 0, 0, 0);
            }
        }

        const bool diag = (jt >= 2 * qt);
        float s[2][4];
        #pragma unroll
        for (int nf = 0; nf < 2; ++nf) {
            float bb_ = mbias[jt * 32 + nf * 16 + l15];
            #pragma unroll
            for (int r = 0; r < 4; ++r) {
                float val = sacc[nf][r] + bb_;
                if (diag) {
                    int gi = qt * 64 + w * 16 + l4 * 4 + r;
                    int gj = jt * 32 + nf * 16 + l15;
                    val = (gj <= gi) ? val : -3e38f;
                }
                s[nf][r] = val;
            }
        }
        float pm[4];
        #pragma unroll
        for (int r = 0; r < 4; ++r) {
            float mx = fmaxf(s[0][r], s[1][r]);
            mx = fmaxf(mx, __shfl_xor(mx, 1));
            mx = fmaxf(mx, __shfl_xor(mx, 2));
            mx = fmaxf(mx, __shfl_xor(mx, 4));
            mx = fmaxf(mx, __shfl_xor(mx, 8));
            pm[r] = mx;
        }
        bool need = false;
        #pragma unroll
        for (int r = 0; r < 4; ++r) need |= (pm[r] - mrow[r] > 8.0f);
        if (__any(need)) {
            #pragma unroll
            for (int r = 0; r < 4; ++r) {
                float mn = fmaxf(mrow[r], pm[r]);
                float corr = __expf(mrow[r] - mn);
                mrow[r] = mn;
                lrow[r] *= corr;
                #pragma unroll
                for (int n = 0; n < 32; ++n) oacc[n][r] *= corr;
            }
        }
        #pragma unroll
        for (int r = 0; r < 4; ++r) {
            float ls = 0.f;
            #pragma unroll
            for (int nf = 0; nf < 2; ++nf) {
                float p = __expf(s[nf][r] - mrow[r]);
                ls += p;
                Pw[w][l4 * 4 + r][nf * 16 + l15] = f2bf(p);
            }
            ls += __shfl_xor(ls, 1);
            ls += __shfl_xor(ls, 2);
            ls += __shfl_xor(ls, 4);
            ls += __shfl_xor(ls, 8);
            lrow[r] += ls;
        }

        const bf16x8 pa = *(const bf16x8*)&Pw[w][l15][l4 * 8];
        const char* Vc = (const char*)&VtL[cur][0];
        #pragma unroll
        for (int n = 0; n < 32; ++n) {
            const bf16x8 vb_ = *(const bf16x8*)(Vc + ((n * 16 + l15) << 6) + (l4 << 4));
            oacc[n] = __builtin_amdgcn_mfma_f32_16x16x32_bf16(pa, vb_, oacc[n], 0, 0, 0);
        }

        if (jt < jtmax) tile_barrier();
    }

    float inv[4];
    #pragma unroll
    for (int r = 0; r < 4; ++r) inv[r] = 1.0f / lrow[r];
    float* op = outp + ((size_t)(b * LL + qt * 64 + w * 16 + l4 * 4)) * DD + l15;
    #pragma unroll
    for (int n = 0; n < 32; ++n)
        #pragma unroll
        for (int r = 0; r < 4; ++r)
            op[(size_t)r * DD + n * 16] = fmaxf(oacc[n][r] * inv[r], 0.f);
    #undef STAGE_KV
}

extern "C" void kernel_launch(void* const* d_in, const int* in_sizes, int n_in,
                              void* d_out, int out_size, void* d_ws, size_t ws_size,
                              hipStream_t stream) {
    const float* x  = (const float*)d_in[0];
    const float* Wq = (const float*)d_in[1];
    const float* bq = (const float*)d_in[2];
    const float* Wk = (const float*)d_in[3];
    const float* bk = (const float*)d_in[4];
    const float* Wv = (const float*)d_in[5];
    const float* bv = (const float*)d_in[6];
    const int* mask = (const int*)d_in[7];

    unsigned short* qkv = (unsigned short*)d_ws;          // q|k|v bf16
    unsigned short* v   = qkv + 2 * MAT;
    unsigned short* vtp = qkv + 3 * MAT;                  // vt region
    unsigned short* Wb  = vtp;                            // parked, overwritten by vtrans
    unsigned short* xb  = (unsigned short*)d_out;         // x bf16 scratch
    float* out = (float*)d_out;

    cast_x<<<16384, 256, 0, stream>>>(x, xb);
    cast_w<<<768, 256, 0, stream>>>(Wq, Wk, Wv, Wb);
    qkv_proj4<<<dim3(256, 3), 512, 0, stream>>>(xb, Wb, bq, bk, bv, qkv);
    vtrans<<<dim3(16, 8, 32), 256, 0, stream>>>(v, vtp);
    attn3<<<dim3(512), 256, 0, stream>>>(qkv, vtp, mask, out);
}